// Round 16
// baseline (1776.175 us; speedup 1.0000x reference)
//
#include <hip/hip_runtime.h>

#define N_ALL 4096
#define N_LAB 1024
#define DIMF 1024
#define EDGECAP 32768
#define ALPHA_ 0.99f
#define NIT_CH 100
#define EPS_D 2.220446049250313e-16

typedef short bf16x8 __attribute__((ext_vector_type(8)));
typedef float f32x4 __attribute__((ext_vector_type(4)));

struct __align__(8) Edge { unsigned j; float w; };

__device__ inline const float* xrow(const float* L, const float* U, int r) {
  return (r < N_LAB) ? (L + (size_t)r * DIMF) : (U + (size_t)(r - N_LAB) * DIMF);
}

__device__ inline void load_lds16(const void* g, void* l) {
  __builtin_amdgcn_global_load_lds(
      (const __attribute__((address_space(1))) unsigned int*)g,
      (__attribute__((address_space(3))) unsigned int*)l, 16, 0, 0);
}

__device__ inline unsigned short bf16rne(float f) {
  unsigned u = __float_as_uint(f);
  unsigned r = (u + 0x7fffu + ((u >> 16) & 1u)) >> 16;
  return (unsigned short)r;
}

// ------- label-layout probe — r15 verbatim -------
__global__ __launch_bounds__(256) void labfmt_k(const int* __restrict__ lab,
                                                int* __restrict__ flag) {
  const long long* l64 = (const long long*)lab;
  int bad = 0;
  for (int k = threadIdx.x; k < 512; k += 256) {
    long long v = l64[k];
    if (v != 0 && v != 1) bad = 1;
  }
  __shared__ int sbad[4];
  unsigned long long m = __ballot(bad);
  if ((threadIdx.x & 63) == 0) sbad[threadIdx.x >> 6] = (m != 0ull);
  __syncthreads();
  if (threadIdx.x == 0)
    flag[0] = (sbad[0] | sbad[1] | sbad[2] | sbad[3]) ? 0 : 1;
}

// ------- prep: fp32 -> bf16 copy + fp32 & fp64 row norms — r15 verbatim -------
__global__ __launch_bounds__(256) void prep_k(const float* __restrict__ L,
                                              const float* __restrict__ U,
                                              unsigned short* __restrict__ Xbf,
                                              float* __restrict__ sq,
                                              double* __restrict__ sqd) {
  const int row = blockIdx.x;
  const int tid = threadIdx.x;
  const float* src = xrow(L, U, row);
  float4 v = ((const float4*)src)[tid];
  ushort4 h;
  h.x = bf16rne(v.x); h.y = bf16rne(v.y); h.z = bf16rne(v.z); h.w = bf16rne(v.w);
  ((ushort4*)(Xbf + (size_t)row * DIMF))[tid] = h;
  float s = v.x * v.x + v.y * v.y + v.z * v.z + v.w * v.w;
  double sd = (double)v.x * v.x + (double)v.y * v.y +
              (double)v.z * v.z + (double)v.w * v.w;
#pragma unroll
  for (int d = 32; d >= 1; d >>= 1) {
    s += __shfl_xor(s, d);
    sd += __shfl_xor(sd, d);
  }
  __shared__ float wsum[4];
  __shared__ double wsumd[4];
  if ((tid & 63) == 0) { wsum[tid >> 6] = s; wsumd[tid >> 6] = sd; }
  __syncthreads();
  if (tid == 0) {
    sq[row] = wsum[0] + wsum[1] + wsum[2] + wsum[3];
    sqd[row] = wsumd[0] + wsumd[1] + wsumd[2] + wsumd[3];
  }
}

// ------- MFMA bf16 gram -> W fp32 — r15 verbatim -------
__global__ __launch_bounds__(256) void gemm_w(const unsigned short* __restrict__ Xbf,
                                              const float* __restrict__ sq,
                                              float* __restrict__ W) {
  __shared__ unsigned short At[128 * 32];
  __shared__ unsigned short Bt[128 * 32];
  const int tid = threadIdx.x;
  const int wave = tid >> 6, lane = tid & 63;
  const int brow = blockIdx.y * 128, bcol = blockIdx.x * 128;
  const int q = lane >> 4, rl = lane & 15;
  const int wr = (wave >> 1) * 64, wc = (wave & 1) * 64;

  f32x4 acc[4][4] = {};

  const int srow = tid >> 2;
  const int soff = (tid & 3) * 8;

  for (int k0 = 0; k0 < DIMF; k0 += 32) {
#pragma unroll
    for (int half = 0; half < 2; ++half) {
      const unsigned short* ga =
          Xbf + (size_t)(brow + half * 64 + srow) * DIMF + k0 + soff;
      load_lds16(ga, &At[(half * 64 + wave * 16) * 32]);
      const unsigned short* gb =
          Xbf + (size_t)(bcol + half * 64 + srow) * DIMF + k0 + soff;
      load_lds16(gb, &Bt[(half * 64 + wave * 16) * 32]);
    }
    __syncthreads();
    bf16x8 af[4], bf_[4];
#pragma unroll
    for (int t = 0; t < 4; ++t) {
      af[t] = *(const bf16x8*)&At[(wr + t * 16 + rl) * 32 + q * 8];
      bf_[t] = *(const bf16x8*)&Bt[(wc + t * 16 + rl) * 32 + q * 8];
    }
#pragma unroll
    for (int i = 0; i < 4; ++i)
#pragma unroll
      for (int j = 0; j < 4; ++j)
        acc[i][j] = __builtin_amdgcn_mfma_f32_16x16x32_bf16(af[i], bf_[j], acc[i][j], 0, 0, 0);
    __syncthreads();
  }

#pragma unroll
  for (int i = 0; i < 4; ++i) {
#pragma unroll
    for (int j = 0; j < 4; ++j) {
#pragma unroll
      for (int reg = 0; reg < 4; ++reg) {
        int gr = brow + wr + i * 16 + q * 4 + reg;
        int gc = bcol + wc + j * 16 + rl;
        float g = acc[i][j][reg];
        float dist = (sq[gr] + sq[gc] - 2.0f * g) * (1.0f / 1024.0f);
        float w = expf(-0.5f * dist);
        if (gr == gc) w = 0.0f;
        W[(size_t)gr * N_ALL + gc] = w;
      }
    }
  }
}

// ------- top-8 candidates per row — r15 verbatim -------
__global__ __launch_bounds__(256) void top8_k(const float* __restrict__ W,
                                              unsigned* __restrict__ t8i) {
  const int wave = threadIdx.x >> 6, lane = threadIdx.x & 63;
  const int row = blockIdx.x * 4 + wave;
  const float* Wr = W + (size_t)row * N_ALL;
  float bv[8]; unsigned bj[8];
#pragma unroll
  for (int t = 0; t < 8; ++t) { bv[t] = -1.0f; bj[t] = 0xFFFFFFFFu; }
  float minv = -1.0f; int mins = 0;
  for (int s = 0; s < 64; ++s) {
    int j = s * 64 + lane;
    float v = Wr[j];
    if (v > minv) {
#pragma unroll
      for (int t = 0; t < 8; ++t) if (t == mins) { bv[t] = v; bj[t] = (unsigned)j; }
      minv = bv[0]; mins = 0;
#pragma unroll
      for (int t = 1; t < 8; ++t) if (bv[t] < minv) { minv = bv[t]; mins = t; }
    }
  }
  for (int pick = 0; pick < 8; ++pick) {
    unsigned long long best = 0;
#pragma unroll
    for (int t = 0; t < 8; ++t) {
      bool valid = (bv[t] >= 0.0f);
      unsigned long long key =
          ((unsigned long long)__float_as_uint(bv[t]) << 32) |
          (unsigned long long)(0xFFFFFFFFu - bj[t]);
      if (valid && key > best) best = key;
    }
#pragma unroll
    for (int d = 32; d >= 1; d >>= 1) {
      unsigned long long o = __shfl_xor(best, d);
      if (o > best) best = o;
    }
    unsigned wj = 0xFFFFFFFFu - (unsigned)(best & 0xFFFFFFFFull);
    if (lane == 0) t8i[row * 8 + pick] = wj;
#pragma unroll
    for (int t = 0; t < 8; ++t) if (bj[t] == wj) bv[t] = -1.0f;
  }
}

// ------- fp64-exact rerank -> exact top-4 — r15 verbatim -------
__global__ __launch_bounds__(256) void rerank_k(const float* __restrict__ L,
                                                const float* __restrict__ U,
                                                const double* __restrict__ sqd,
                                                const unsigned* __restrict__ t8i,
                                                unsigned* __restrict__ t4i) {
  const int wave = threadIdx.x >> 6, lane = threadIdx.x & 63;
  const int row = blockIdx.x * 4 + wave;
  const float* xi = xrow(L, U, row);
  float xr[16];
#pragma unroll
  for (int t = 0; t < 16; ++t) xr[t] = xi[t * 64 + lane];
  unsigned cj[8];
  double cw[8];
#pragma unroll
  for (int c = 0; c < 8; ++c) cj[c] = t8i[row * 8 + c];
  for (int c = 0; c < 8; ++c) {
    const float* xj = xrow(L, U, (int)cj[c]);
    double s = 0.0;
#pragma unroll
    for (int t = 0; t < 16; ++t) s += (double)xr[t] * xj[t * 64 + lane];
#pragma unroll
    for (int d = 32; d >= 1; d >>= 1) s += __shfl_xor(s, d);
    double dist = (sqd[row] + sqd[cj[c]] - 2.0 * s) * (1.0 / 1024.0);
    cw[c] = exp(-0.5 * dist);
  }
  if (lane == 0) {
#pragma unroll
    for (int pick = 0; pick < 4; ++pick) {
      int ms = -1;
      double mv = -1.0;
      unsigned mj = 0xFFFFFFFFu;
#pragma unroll
      for (int c = 0; c < 8; ++c) {
        bool better = (cw[c] > mv) || (cw[c] == mv && cj[c] < mj);
        if (cw[c] >= 0.0 && better) { mv = cw[c]; mj = cj[c]; ms = c; }
      }
      t4i[row * 4 + pick] = mj;
      cw[ms] = -2.0;
    }
  }
}

// ------- count kept edges per row — r15 verbatim -------
__global__ __launch_bounds__(256) void cnt4_k(const unsigned* __restrict__ t4i,
                                              unsigned* __restrict__ nn) {
  const int wave = threadIdx.x >> 6, lane = threadIdx.x & 63;
  const int i = blockIdx.x * 4 + wave;
  const uint4 mine = ((const uint4*)t4i)[i];
  unsigned base = 0;
  for (int j0 = 0; j0 < N_ALL; j0 += 64) {
    int j = j0 + lane;
    uint4 tj = ((const uint4*)t4i)[j];
    bool keep = (mine.x == (unsigned)j) | (mine.y == (unsigned)j) |
                (mine.z == (unsigned)j) | (mine.w == (unsigned)j) |
                (tj.x == (unsigned)i) | (tj.y == (unsigned)i) |
                (tj.z == (unsigned)i) | (tj.w == (unsigned)i);
    keep = keep && (j != i);
    base += (unsigned)__popcll(__ballot(keep));
  }
  if (lane == 0) nn[i] = base;
}

// ------- exclusive scan of nn -> CSR rowPtr — r15 verbatim -------
__global__ __launch_bounds__(64) void scanP_k(const unsigned* __restrict__ nn,
                                              unsigned* __restrict__ rowPtr) {
  const int lane = threadIdx.x;
  unsigned running = 0;
  for (int j0 = 0; j0 < N_ALL; j0 += 64) {
    int v = (int)nn[j0 + lane];
    int incl = v;
#pragma unroll
    for (int d = 1; d < 64; d <<= 1) {
      int t = __shfl_up(incl, d);
      if (lane >= d) incl += t;
    }
    rowPtr[j0 + lane] = running + (unsigned)(incl - v);
    running += (unsigned)__shfl(incl, 63);
  }
  if (lane == 0) rowPtr[N_ALL] = running;
}

// ------- CSR index fill — r15 verbatim -------
__global__ __launch_bounds__(256) void csrfill_k(const unsigned* __restrict__ t4i,
                                                 const unsigned* __restrict__ rowPtr,
                                                 Edge* __restrict__ edges,
                                                 unsigned* __restrict__ eRow) {
  const int wave = threadIdx.x >> 6, lane = threadIdx.x & 63;
  const int i = blockIdx.x * 4 + wave;
  const uint4 mine = ((const uint4*)t4i)[i];
  unsigned base = rowPtr[i];
  for (int j0 = 0; j0 < N_ALL; j0 += 64) {
    int j = j0 + lane;
    uint4 tj = ((const uint4*)t4i)[j];
    bool keep = (mine.x == (unsigned)j) | (mine.y == (unsigned)j) |
                (mine.z == (unsigned)j) | (mine.w == (unsigned)j) |
                (tj.x == (unsigned)i) | (tj.y == (unsigned)i) |
                (tj.z == (unsigned)i) | (tj.w == (unsigned)i);
    keep = keep && (j != i);
    unsigned long long m = __ballot(keep);
    if (keep) {
      unsigned pos = base + (unsigned)__popcll(m & ((1ull << lane) - 1ull));
      edges[pos].j = (unsigned)j;
      edges[pos].w = 0.0f;
      eRow[pos] = (unsigned)i;
    }
    base += (unsigned)__popcll(m);
  }
}

// ------- exact edge values — r15 verbatim -------
__global__ __launch_bounds__(256) void edgeval_k(const float* __restrict__ L,
                                                 const float* __restrict__ U,
                                                 const double* __restrict__ sqd,
                                                 const unsigned* __restrict__ rowPtr,
                                                 const unsigned* __restrict__ eRow,
                                                 Edge* __restrict__ edges) {
  const int wave = threadIdx.x >> 6, lane = threadIdx.x & 63;
  const unsigned e = blockIdx.x * 4 + wave;
  if (e >= rowPtr[N_ALL]) return;
  const unsigned i = eRow[e];
  const unsigned j = edges[e].j;
  const float* xi = xrow(L, U, (int)i);
  const float* xj = xrow(L, U, (int)j);
  double s = 0.0;
#pragma unroll
  for (int t = 0; t < 16; ++t)
    s += (double)xi[t * 64 + lane] * xj[t * 64 + lane];
#pragma unroll
  for (int d = 32; d >= 1; d >>= 1) s += __shfl_xor(s, d);
  if (lane == 0) {
    double dist = (sqd[i] + sqd[j] - 2.0 * s) * (1.0 / 1024.0);
    edges[e].w = (float)exp(-0.5 * dist);
  }
}

// ------- degrees from exact edge values — r15 verbatim -------
__global__ __launch_bounds__(256) void degE_k(const unsigned* __restrict__ rowPtr,
                                              const Edge* __restrict__ edges,
                                              float* __restrict__ Dis) {
  const int wave = threadIdx.x >> 6, lane = threadIdx.x & 63;
  const int i = blockIdx.x * 4 + wave;
  const unsigned b0 = rowPtr[i], b1 = rowPtr[i + 1];
  double ds = 0.0;
  for (unsigned e = b0 + lane; e < b1; e += 64) ds += (double)edges[e].w;
#pragma unroll
  for (int d = 32; d >= 1; d >>= 1) ds += __shfl_xor(ds, d);
  if (lane == 0) Dis[i] = (float)sqrt(1.0 / (ds + EPS_D));
}

// ------- scale edges — r15 verbatim -------
__global__ __launch_bounds__(256) void scaleE_k(const unsigned* __restrict__ rowPtr,
                                                const unsigned* __restrict__ eRow,
                                                const float* __restrict__ Dis,
                                                Edge* __restrict__ edges) {
  const unsigned e = blockIdx.x * 256 + threadIdx.x;
  if (e >= rowPtr[N_ALL]) return;
  Edge ed = edges[e];
  edges[e].w = ed.w * Dis[eRow[e]] * Dis[ed.j];
}

// ------- repack CSR into thread-major arrays (thread t owns pos [32t,32t+32)) -------
__global__ __launch_bounds__(256) void repack_k(const Edge* __restrict__ edges,
                                                const unsigned* __restrict__ eRow,
                                                const unsigned* __restrict__ rowPtr,
                                                unsigned short* __restrict__ jT,
                                                float* __restrict__ wT,
                                                unsigned short* __restrict__ rowT) {
  const unsigned pos = blockIdx.x * 256 + threadIdx.x;
  const unsigned nnz = rowPtr[N_ALL];
  const unsigned slot = (pos & 31) * 1024 + (pos >> 5);
  if (pos < nnz) {
    jT[slot] = (unsigned short)edges[pos].j;
    wT[slot] = edges[pos].w;
    rowT[slot] = (unsigned short)eRow[pos];
  } else {
    jT[slot] = 0;
    wT[slot] = 0.0f;
    rowT[slot] = 0;  // pad: adds 0.0 to acc[0] — harmless
  }
}

// ---- ONE-LAUNCH single-block Chebyshev: per-edge parallel SpMV, LDS atomics ----
// Thread t owns 32 contiguous CSR positions; rows in CSR are consecutive
// (every row has >=4 edges), so flush targets are r0 + running flush count.
__global__ __launch_bounds__(1024) void cheb_solve(const int* __restrict__ lab,
                                                   const int* __restrict__ labflag,
                                                   const unsigned short* __restrict__ jT,
                                                   const float* __restrict__ wT,
                                                   const unsigned short* __restrict__ rowT,
                                                   float2* __restrict__ out) {
  __shared__ float2 dS[N_ALL];
  __shared__ float2 acc[N_ALL];
  const int tid = threadIdx.x;
  const int isI64 = labflag[0];
  float2 x[4], rv[4], dv[4];
#pragma unroll
  for (int u = 0; u < 4; ++u) {
    int m = tid + u * 1024;
    float2 b = make_float2(0.0f, 0.0f);
    if (m < N_LAB) {
      int c = isI64 ? lab[2 * m] : lab[m];
      b.x = (c == 0) ? 1.0f : 0.0f;
      b.y = (c == 1) ? 1.0f : 0.0f;
    }
    x[u] = make_float2(0.0f, 0.0f);
    rv[u] = b;
    dv[u] = b;  // d = r/theta, theta = 1
    dS[m] = b;
    acc[m] = make_float2(0.0f, 0.0f);
  }
  // flush mask + first row (32 coalesced u16 loads, once)
  int prevRow = (int)rowT[tid];
  const int r0 = prevRow;
  unsigned mask = 0;
#pragma unroll
  for (int k = 1; k < 32; ++k) {
    int rw = (int)rowT[k * 1024 + tid];
    if (rw != prevRow) mask |= 1u << (k - 1);
    prevRow = rw;
  }
  mask |= 1u << 31;
  __syncthreads();

  const double theta = 1.0, delta = 0.992;
  const double sigma1 = theta / delta;
  double rho = delta / theta;
  for (int it = 0;; ++it) {
    // phase 1: per-edge SpMV with register run-accumulation + LDS atomic flush
    float ax = 0.0f, ay = 0.0f;
    int fl = 0;
#pragma unroll
    for (int k = 0; k < 32; ++k) {
      const int idx = k * 1024 + tid;
      float wv = wT[idx];
      int j = (int)jT[idx];
      float2 dj = dS[j];
      ax += wv * dj.x;
      ay += wv * dj.y;
      if ((mask >> k) & 1u) {
        atomicAdd(&acc[r0 + fl].x, ax);
        atomicAdd(&acc[r0 + fl].y, ay);
        ax = 0.0f; ay = 0.0f;
        ++fl;
      }
    }
    __syncthreads();
    // phase 2: per-row update (owner reads+resets acc, updates x/r/d, publishes dS)
    const bool last = (it == NIT_CH - 1);
    const double rho_new = 1.0 / (2.0 * sigma1 - rho);
    const float c1 = (float)(rho_new * rho);
    const float c2 = (float)(2.0 * rho_new / delta);
    rho = rho_new;
#pragma unroll
    for (int u = 0; u < 4; ++u) {
      int m = tid + u * 1024;
      float2 a = acc[m];
      acc[m] = make_float2(0.0f, 0.0f);
      x[u].x += dv[u].x; x[u].y += dv[u].y;
      rv[u].x += ALPHA_ * a.x - dv[u].x;
      rv[u].y += ALPHA_ * a.y - dv[u].y;
      if (!last) {
        dv[u].x = c1 * dv[u].x + c2 * rv[u].x;
        dv[u].y = c1 * dv[u].y + c2 * rv[u].y;
        dS[m] = dv[u];
      }
    }
    if (last) break;
    __syncthreads();
  }
#pragma unroll
  for (int u = 1; u < 4; ++u) {
    int m = tid + u * 1024;
    out[m - N_LAB] = x[u];
  }
}

// ---------------- launch ----------------
extern "C" void kernel_launch(void* const* d_in, const int* in_sizes, int n_in,
                              void* d_out, int out_size, void* d_ws, size_t ws_size,
                              hipStream_t stream) {
  int iL = 0, iT = 1, iU = 2;
  for (int i = 0; i < n_in; ++i) {
    if (in_sizes[i] == N_LAB * DIMF) iL = i;
    else if (in_sizes[i] == (N_ALL - N_LAB) * DIMF) iU = i;
    else iT = i;
  }
  const float* L = (const float*)d_in[iL];
  const int* lab = (const int*)d_in[iT];
  const float* U = (const float*)d_in[iU];
  float2* out = (float2*)d_out;

  char* w = (char*)d_ws;
  size_t off = 0;
  auto alloc = [&](size_t bytes) {
    void* p = (void*)(w + off);
    off += (bytes + 255) & ~(size_t)255;
    return p;
  };
  float* W = (float*)alloc((size_t)N_ALL * N_ALL * 4);            // 64 MB
  unsigned short* Xbf = (unsigned short*)alloc((size_t)N_ALL * DIMF * 2);  // 8 MB
  float* sq = (float*)alloc(N_ALL * 4);
  double* sqd = (double*)alloc(N_ALL * 8);
  unsigned* t8i = (unsigned*)alloc(N_ALL * 8 * 4);
  unsigned* t4i = (unsigned*)alloc(N_ALL * 4 * 4);
  float* Dis = (float*)alloc(N_ALL * 4);
  unsigned* nn = (unsigned*)alloc(N_ALL * 4);
  unsigned* rowPtr = (unsigned*)alloc((N_ALL + 1) * 4);
  int* labflag = (int*)alloc(256);
  Edge* edges = (Edge*)alloc((size_t)EDGECAP * sizeof(Edge));     // 256 KB
  unsigned* eRow = (unsigned*)alloc((size_t)EDGECAP * 4);         // 128 KB
  unsigned short* jT = (unsigned short*)alloc((size_t)EDGECAP * 2);   // 64 KB
  float* wT = (float*)alloc((size_t)EDGECAP * 4);                     // 128 KB
  unsigned short* rowT = (unsigned short*)alloc((size_t)EDGECAP * 2); // 64 KB
  if (off > ws_size) return;

  labfmt_k<<<1, 256, 0, stream>>>(lab, labflag);
  prep_k<<<N_ALL, 256, 0, stream>>>(L, U, Xbf, sq, sqd);
  gemm_w<<<dim3(32, 32), 256, 0, stream>>>(Xbf, sq, W);
  top8_k<<<N_ALL / 4, 256, 0, stream>>>(W, t8i);
  rerank_k<<<N_ALL / 4, 256, 0, stream>>>(L, U, sqd, t8i, t4i);
  cnt4_k<<<N_ALL / 4, 256, 0, stream>>>(t4i, nn);
  scanP_k<<<1, 64, 0, stream>>>(nn, rowPtr);
  csrfill_k<<<N_ALL / 4, 256, 0, stream>>>(t4i, rowPtr, edges, eRow);
  edgeval_k<<<EDGECAP / 4, 256, 0, stream>>>(L, U, sqd, rowPtr, eRow, edges);
  degE_k<<<N_ALL / 4, 256, 0, stream>>>(rowPtr, edges, Dis);
  scaleE_k<<<EDGECAP / 256, 256, 0, stream>>>(rowPtr, eRow, Dis, edges);
  repack_k<<<EDGECAP / 256, 256, 0, stream>>>(edges, eRow, rowPtr, jT, wT, rowT);
  cheb_solve<<<1, 1024, 0, stream>>>(lab, labflag, jT, wT, rowT, out);
}

// Round 17
// 556.099 us; speedup vs baseline: 3.1940x; 3.1940x over previous
//
#include <hip/hip_runtime.h>

#define N_ALL 4096
#define N_LAB 1024
#define DIMF 1024
#define EDGECAP 32768
#define ALPHA_ 0.99f
#define NIT_CH 80
#define EPS_D 2.220446049250313e-16

typedef short bf16x8 __attribute__((ext_vector_type(8)));
typedef float f32x4 __attribute__((ext_vector_type(4)));

struct __align__(8) Edge { unsigned j; float w; };

__device__ inline const float* xrow(const float* L, const float* U, int r) {
  return (r < N_LAB) ? (L + (size_t)r * DIMF) : (U + (size_t)(r - N_LAB) * DIMF);
}

__device__ inline void load_lds16(const void* g, void* l) {
  __builtin_amdgcn_global_load_lds(
      (const __attribute__((address_space(1))) unsigned int*)g,
      (__attribute__((address_space(3))) unsigned int*)l, 16, 0, 0);
}

__device__ inline unsigned short bf16rne(float f) {
  unsigned u = __float_as_uint(f);
  unsigned r = (u + 0x7fffu + ((u >> 16) & 1u)) >> 16;
  return (unsigned short)r;
}

// ------- prep: fp32 -> bf16 copy + fp32 & fp64 row norms — r15 verbatim -------
__global__ __launch_bounds__(256) void prep_k(const float* __restrict__ L,
                                              const float* __restrict__ U,
                                              unsigned short* __restrict__ Xbf,
                                              float* __restrict__ sq,
                                              double* __restrict__ sqd) {
  const int row = blockIdx.x;
  const int tid = threadIdx.x;
  const float* src = xrow(L, U, row);
  float4 v = ((const float4*)src)[tid];
  ushort4 h;
  h.x = bf16rne(v.x); h.y = bf16rne(v.y); h.z = bf16rne(v.z); h.w = bf16rne(v.w);
  ((ushort4*)(Xbf + (size_t)row * DIMF))[tid] = h;
  float s = v.x * v.x + v.y * v.y + v.z * v.z + v.w * v.w;
  double sd = (double)v.x * v.x + (double)v.y * v.y +
              (double)v.z * v.z + (double)v.w * v.w;
#pragma unroll
  for (int d = 32; d >= 1; d >>= 1) {
    s += __shfl_xor(s, d);
    sd += __shfl_xor(sd, d);
  }
  __shared__ float wsum[4];
  __shared__ double wsumd[4];
  if ((tid & 63) == 0) { wsum[tid >> 6] = s; wsumd[tid >> 6] = sd; }
  __syncthreads();
  if (tid == 0) {
    sq[row] = wsum[0] + wsum[1] + wsum[2] + wsum[3];
    sqd[row] = wsumd[0] + wsumd[1] + wsumd[2] + wsumd[3];
  }
}

// ------- MFMA bf16 gram -> fp16 RANKING PROXY (no exp; monotone in W) -------
// val = max(2600 - unnormalized_dist, 0.25); diag = 0. exp is monotone
// decreasing in dist, so top-8 by val == top-8 by W (up to proxy rounding,
// which the fp64 rerank absorbs).
__global__ __launch_bounds__(256) void gemm_w(const unsigned short* __restrict__ Xbf,
                                              const float* __restrict__ sq,
                                              _Float16* __restrict__ Wh) {
  __shared__ unsigned short At[128 * 32];
  __shared__ unsigned short Bt[128 * 32];
  const int tid = threadIdx.x;
  const int wave = tid >> 6, lane = tid & 63;
  const int brow = blockIdx.y * 128, bcol = blockIdx.x * 128;
  const int q = lane >> 4, rl = lane & 15;
  const int wr = (wave >> 1) * 64, wc = (wave & 1) * 64;

  f32x4 acc[4][4] = {};

  const int srow = tid >> 2;
  const int soff = (tid & 3) * 8;

  for (int k0 = 0; k0 < DIMF; k0 += 32) {
#pragma unroll
    for (int half = 0; half < 2; ++half) {
      const unsigned short* ga =
          Xbf + (size_t)(brow + half * 64 + srow) * DIMF + k0 + soff;
      load_lds16(ga, &At[(half * 64 + wave * 16) * 32]);
      const unsigned short* gb =
          Xbf + (size_t)(bcol + half * 64 + srow) * DIMF + k0 + soff;
      load_lds16(gb, &Bt[(half * 64 + wave * 16) * 32]);
    }
    __syncthreads();
    bf16x8 af[4], bf_[4];
#pragma unroll
    for (int t = 0; t < 4; ++t) {
      af[t] = *(const bf16x8*)&At[(wr + t * 16 + rl) * 32 + q * 8];
      bf_[t] = *(const bf16x8*)&Bt[(wc + t * 16 + rl) * 32 + q * 8];
    }
#pragma unroll
    for (int i = 0; i < 4; ++i)
#pragma unroll
      for (int j = 0; j < 4; ++j)
        acc[i][j] = __builtin_amdgcn_mfma_f32_16x16x32_bf16(af[i], bf_[j], acc[i][j], 0, 0, 0);
    __syncthreads();
  }

#pragma unroll
  for (int i = 0; i < 4; ++i) {
#pragma unroll
    for (int j = 0; j < 4; ++j) {
#pragma unroll
      for (int reg = 0; reg < 4; ++reg) {
        int gr = brow + wr + i * 16 + q * 4 + reg;
        int gc = bcol + wc + j * 16 + rl;
        float g = acc[i][j][reg];
        float dist = sq[gr] + sq[gc] - 2.0f * g;   // unnormalized
        float val = fmaxf(2600.0f - dist, 0.25f);
        if (gr == gc) val = 0.0f;
        Wh[(size_t)gr * N_ALL + gc] = (_Float16)val;
      }
    }
  }
}

// ------- top-8 candidates per row (fp16 proxy), single scan -------
__global__ __launch_bounds__(256) void top8_k(const _Float16* __restrict__ Wh,
                                              unsigned* __restrict__ t8i) {
  const int wave = threadIdx.x >> 6, lane = threadIdx.x & 63;
  const int row = blockIdx.x * 4 + wave;
  const _Float16* Wr = Wh + (size_t)row * N_ALL;
  float bv[8]; unsigned bj[8];
#pragma unroll
  for (int t = 0; t < 8; ++t) { bv[t] = -1.0f; bj[t] = 0xFFFFFFFFu; }
  float minv = -1.0f; int mins = 0;
  for (int s = 0; s < 64; ++s) {
    int j = s * 64 + lane;
    float v = (float)Wr[j];
    if (v > minv) {
#pragma unroll
      for (int t = 0; t < 8; ++t) if (t == mins) { bv[t] = v; bj[t] = (unsigned)j; }
      minv = bv[0]; mins = 0;
#pragma unroll
      for (int t = 1; t < 8; ++t) if (bv[t] < minv) { minv = bv[t]; mins = t; }
    }
  }
  for (int pick = 0; pick < 8; ++pick) {
    unsigned long long best = 0;
#pragma unroll
    for (int t = 0; t < 8; ++t) {
      bool valid = (bv[t] >= 0.0f);
      unsigned long long key =
          ((unsigned long long)__float_as_uint(bv[t]) << 32) |
          (unsigned long long)(0xFFFFFFFFu - bj[t]);
      if (valid && key > best) best = key;
    }
#pragma unroll
    for (int d = 32; d >= 1; d >>= 1) {
      unsigned long long o = __shfl_xor(best, d);
      if (o > best) best = o;
    }
    unsigned wj = 0xFFFFFFFFu - (unsigned)(best & 0xFFFFFFFFull);
    if (lane == 0) t8i[row * 8 + pick] = wj;
#pragma unroll
    for (int t = 0; t < 8; ++t) if (bj[t] == wj) bv[t] = -1.0f;
  }
}

// ------- fp64-exact rerank -> exact top-4 — r15 verbatim -------
__global__ __launch_bounds__(256) void rerank_k(const float* __restrict__ L,
                                                const float* __restrict__ U,
                                                const double* __restrict__ sqd,
                                                const unsigned* __restrict__ t8i,
                                                unsigned* __restrict__ t4i) {
  const int wave = threadIdx.x >> 6, lane = threadIdx.x & 63;
  const int row = blockIdx.x * 4 + wave;
  const float* xi = xrow(L, U, row);
  float xr[16];
#pragma unroll
  for (int t = 0; t < 16; ++t) xr[t] = xi[t * 64 + lane];
  unsigned cj[8];
  double cw[8];
#pragma unroll
  for (int c = 0; c < 8; ++c) cj[c] = t8i[row * 8 + c];
  for (int c = 0; c < 8; ++c) {
    const float* xj = xrow(L, U, (int)cj[c]);
    double s = 0.0;
#pragma unroll
    for (int t = 0; t < 16; ++t) s += (double)xr[t] * xj[t * 64 + lane];
#pragma unroll
    for (int d = 32; d >= 1; d >>= 1) s += __shfl_xor(s, d);
    double dist = (sqd[row] + sqd[cj[c]] - 2.0 * s) * (1.0 / 1024.0);
    cw[c] = exp(-0.5 * dist);
  }
  if (lane == 0) {
#pragma unroll
    for (int pick = 0; pick < 4; ++pick) {
      int ms = -1;
      double mv = -1.0;
      unsigned mj = 0xFFFFFFFFu;
#pragma unroll
      for (int c = 0; c < 8; ++c) {
        bool better = (cw[c] > mv) || (cw[c] == mv && cj[c] < mj);
        if (cw[c] >= 0.0 && better) { mv = cw[c]; mj = cj[c]; ms = c; }
      }
      t4i[row * 4 + pick] = mj;
      cw[ms] = -2.0;
    }
  }
}

// ------- count kept edges per row — r15 verbatim -------
__global__ __launch_bounds__(256) void cnt4_k(const unsigned* __restrict__ t4i,
                                              unsigned* __restrict__ nn) {
  const int wave = threadIdx.x >> 6, lane = threadIdx.x & 63;
  const int i = blockIdx.x * 4 + wave;
  const uint4 mine = ((const uint4*)t4i)[i];
  unsigned base = 0;
  for (int j0 = 0; j0 < N_ALL; j0 += 64) {
    int j = j0 + lane;
    uint4 tj = ((const uint4*)t4i)[j];
    bool keep = (mine.x == (unsigned)j) | (mine.y == (unsigned)j) |
                (mine.z == (unsigned)j) | (mine.w == (unsigned)j) |
                (tj.x == (unsigned)i) | (tj.y == (unsigned)i) |
                (tj.z == (unsigned)i) | (tj.w == (unsigned)i);
    keep = keep && (j != i);
    base += (unsigned)__popcll(__ballot(keep));
  }
  if (lane == 0) nn[i] = base;
}

// ------- exclusive scan of nn -> CSR rowPtr + label-layout probe (fused) -------
__global__ __launch_bounds__(64) void scanP_k(const unsigned* __restrict__ nn,
                                              unsigned* __restrict__ rowPtr,
                                              const int* __restrict__ lab,
                                              int* __restrict__ labflag) {
  const int lane = threadIdx.x;
  // label probe: first 4096 bytes as 512 int64; any value not in {0,1} -> int32
  const long long* l64 = (const long long*)lab;
  int bad = 0;
#pragma unroll
  for (int k = 0; k < 8; ++k) {
    long long v = l64[k * 64 + lane];
    if (v != 0 && v != 1) bad = 1;
  }
  unsigned long long bm = __ballot(bad);
  if (lane == 0) labflag[0] = (bm != 0ull) ? 0 : 1;
  unsigned running = 0;
  for (int j0 = 0; j0 < N_ALL; j0 += 64) {
    int v = (int)nn[j0 + lane];
    int incl = v;
#pragma unroll
    for (int d = 1; d < 64; d <<= 1) {
      int t = __shfl_up(incl, d);
      if (lane >= d) incl += t;
    }
    rowPtr[j0 + lane] = running + (unsigned)(incl - v);
    running += (unsigned)__shfl(incl, 63);
  }
  if (lane == 0) rowPtr[N_ALL] = running;
}

// ------- CSR index fill — r15 verbatim -------
__global__ __launch_bounds__(256) void csrfill_k(const unsigned* __restrict__ t4i,
                                                 const unsigned* __restrict__ rowPtr,
                                                 Edge* __restrict__ edges,
                                                 unsigned* __restrict__ eRow) {
  const int wave = threadIdx.x >> 6, lane = threadIdx.x & 63;
  const int i = blockIdx.x * 4 + wave;
  const uint4 mine = ((const uint4*)t4i)[i];
  unsigned base = rowPtr[i];
  for (int j0 = 0; j0 < N_ALL; j0 += 64) {
    int j = j0 + lane;
    uint4 tj = ((const uint4*)t4i)[j];
    bool keep = (mine.x == (unsigned)j) | (mine.y == (unsigned)j) |
                (mine.z == (unsigned)j) | (mine.w == (unsigned)j) |
                (tj.x == (unsigned)i) | (tj.y == (unsigned)i) |
                (tj.z == (unsigned)i) | (tj.w == (unsigned)i);
    keep = keep && (j != i);
    unsigned long long m = __ballot(keep);
    if (keep) {
      unsigned pos = base + (unsigned)__popcll(m & ((1ull << lane) - 1ull));
      edges[pos].j = (unsigned)j;
      edges[pos].w = 0.0f;
      eRow[pos] = (unsigned)i;
    }
    base += (unsigned)__popcll(m);
  }
}

// ------- exact edge values — r15 verbatim -------
__global__ __launch_bounds__(256) void edgeval_k(const float* __restrict__ L,
                                                 const float* __restrict__ U,
                                                 const double* __restrict__ sqd,
                                                 const unsigned* __restrict__ rowPtr,
                                                 const unsigned* __restrict__ eRow,
                                                 Edge* __restrict__ edges) {
  const int wave = threadIdx.x >> 6, lane = threadIdx.x & 63;
  const unsigned e = blockIdx.x * 4 + wave;
  if (e >= rowPtr[N_ALL]) return;
  const unsigned i = eRow[e];
  const unsigned j = edges[e].j;
  const float* xi = xrow(L, U, (int)i);
  const float* xj = xrow(L, U, (int)j);
  double s = 0.0;
#pragma unroll
  for (int t = 0; t < 16; ++t)
    s += (double)xi[t * 64 + lane] * xj[t * 64 + lane];
#pragma unroll
  for (int d = 32; d >= 1; d >>= 1) s += __shfl_xor(s, d);
  if (lane == 0) {
    double dist = (sqd[i] + sqd[j] - 2.0 * s) * (1.0 / 1024.0);
    edges[e].w = (float)exp(-0.5 * dist);
  }
}

// ------- degrees from exact edge values — r15 verbatim -------
__global__ __launch_bounds__(256) void degE_k(const unsigned* __restrict__ rowPtr,
                                              const Edge* __restrict__ edges,
                                              float* __restrict__ Dis) {
  const int wave = threadIdx.x >> 6, lane = threadIdx.x & 63;
  const int i = blockIdx.x * 4 + wave;
  const unsigned b0 = rowPtr[i], b1 = rowPtr[i + 1];
  double ds = 0.0;
  for (unsigned e = b0 + lane; e < b1; e += 64) ds += (double)edges[e].w;
#pragma unroll
  for (int d = 32; d >= 1; d >>= 1) ds += __shfl_xor(ds, d);
  if (lane == 0) Dis[i] = (float)sqrt(1.0 / (ds + EPS_D));
}

// ------- scale edges — r15 verbatim -------
__global__ __launch_bounds__(256) void scaleE_k(const unsigned* __restrict__ rowPtr,
                                                const unsigned* __restrict__ eRow,
                                                const float* __restrict__ Dis,
                                                Edge* __restrict__ edges) {
  const unsigned e = blockIdx.x * 256 + threadIdx.x;
  if (e >= rowPtr[N_ALL]) return;
  Edge ed = edges[e];
  edges[e].w = ed.w * Dis[eRow[e]] * Dis[ed.j];
}

// ------- Chebyshev state init — r15 verbatim -------
__global__ __launch_bounds__(256) void init_k(const int* __restrict__ lab,
                                              const int* __restrict__ labflag,
                                              float2* __restrict__ x,
                                              float2* __restrict__ r,
                                              float2* __restrict__ d) {
  const int m = blockIdx.x * 256 + threadIdx.x;
  const int isI64 = labflag[0];
  float2 b = make_float2(0.0f, 0.0f);
  if (m < N_LAB) {
    int c = isI64 ? lab[2 * m] : lab[m];
    b.x = (c == 0) ? 1.0f : 0.0f;
    b.y = (c == 1) ? 1.0f : 0.0f;
  }
  x[m] = make_float2(0.0f, 0.0f);
  r[m] = b;
  d[m] = b;
}

// ---- one Chebyshev iteration — r15 verbatim ----
__global__ __launch_bounds__(512) void chebit_k(const Edge* __restrict__ edges,
                                                const unsigned* __restrict__ rowPtr,
                                                const float2* __restrict__ dIn,
                                                float2* __restrict__ dOut,
                                                float2* __restrict__ x,
                                                float2* __restrict__ r,
                                                float c1, float c2, int last) {
  const int row = blockIdx.x * 8 + (threadIdx.x >> 6);
  const int lane = threadIdx.x & 63;
  const unsigned b0 = rowPtr[row], b1 = rowPtr[row + 1];
  float ax = 0.0f, ay = 0.0f;
  for (unsigned e = b0 + lane; e < b1; e += 64) {
    Edge ed = edges[e];
    float2 dj = dIn[ed.j];
    ax += ed.w * dj.x;
    ay += ed.w * dj.y;
  }
#pragma unroll
  for (int d = 32; d >= 1; d >>= 1) {
    ax += __shfl_xor(ax, d);
    ay += __shfl_xor(ay, d);
  }
  if (lane == 0) {
    float2 di = dIn[row], xi = x[row], ri = r[row];
    xi.x += di.x; xi.y += di.y;
    ri.x += ALPHA_ * ax - di.x;
    ri.y += ALPHA_ * ay - di.y;
    x[row] = xi;
    r[row] = ri;
    if (!last) {
      float2 dn;
      dn.x = c1 * di.x + c2 * ri.x;
      dn.y = c1 * di.y + c2 * ri.y;
      dOut[row] = dn;
    }
  }
}

// ------- emit queries — r15 verbatim -------
__global__ __launch_bounds__(256) void out_k(const float2* __restrict__ x,
                                             float2* __restrict__ out) {
  const int q = blockIdx.x * 256 + threadIdx.x;
  out[q] = x[N_LAB + q];
}

// ---------------- launch ----------------
extern "C" void kernel_launch(void* const* d_in, const int* in_sizes, int n_in,
                              void* d_out, int out_size, void* d_ws, size_t ws_size,
                              hipStream_t stream) {
  int iL = 0, iT = 1, iU = 2;
  for (int i = 0; i < n_in; ++i) {
    if (in_sizes[i] == N_LAB * DIMF) iL = i;
    else if (in_sizes[i] == (N_ALL - N_LAB) * DIMF) iU = i;
    else iT = i;
  }
  const float* L = (const float*)d_in[iL];
  const int* lab = (const int*)d_in[iT];
  const float* U = (const float*)d_in[iU];
  float2* out = (float2*)d_out;

  char* w = (char*)d_ws;
  size_t off = 0;
  auto alloc = [&](size_t bytes) {
    void* p = (void*)(w + off);
    off += (bytes + 255) & ~(size_t)255;
    return p;
  };
  _Float16* Wh = (_Float16*)alloc((size_t)N_ALL * N_ALL * 2);     // 32 MB proxy
  unsigned short* Xbf = (unsigned short*)alloc((size_t)N_ALL * DIMF * 2);  // 8 MB
  float* sq = (float*)alloc(N_ALL * 4);
  double* sqd = (double*)alloc(N_ALL * 8);
  unsigned* t8i = (unsigned*)alloc(N_ALL * 8 * 4);
  unsigned* t4i = (unsigned*)alloc(N_ALL * 4 * 4);
  float* Dis = (float*)alloc(N_ALL * 4);
  unsigned* nn = (unsigned*)alloc(N_ALL * 4);
  unsigned* rowPtr = (unsigned*)alloc((N_ALL + 1) * 4);
  int* labflag = (int*)alloc(256);
  Edge* edges = (Edge*)alloc((size_t)EDGECAP * sizeof(Edge));     // 256 KB
  unsigned* eRow = (unsigned*)alloc((size_t)EDGECAP * 4);         // 128 KB
  float2* xv = (float2*)alloc(N_ALL * 8);
  float2* rv = (float2*)alloc(N_ALL * 8);
  float2* dv0 = (float2*)alloc(N_ALL * 8);
  float2* dv1 = (float2*)alloc(N_ALL * 8);
  if (off > ws_size) return;

  prep_k<<<N_ALL, 256, 0, stream>>>(L, U, Xbf, sq, sqd);
  gemm_w<<<dim3(32, 32), 256, 0, stream>>>(Xbf, sq, Wh);
  top8_k<<<N_ALL / 4, 256, 0, stream>>>(Wh, t8i);
  rerank_k<<<N_ALL / 4, 256, 0, stream>>>(L, U, sqd, t8i, t4i);
  cnt4_k<<<N_ALL / 4, 256, 0, stream>>>(t4i, nn);
  scanP_k<<<1, 64, 0, stream>>>(nn, rowPtr, lab, labflag);
  csrfill_k<<<N_ALL / 4, 256, 0, stream>>>(t4i, rowPtr, edges, eRow);
  edgeval_k<<<EDGECAP / 4, 256, 0, stream>>>(L, U, sqd, rowPtr, eRow, edges);
  degE_k<<<N_ALL / 4, 256, 0, stream>>>(rowPtr, edges, Dis);
  scaleE_k<<<EDGECAP / 256, 256, 0, stream>>>(rowPtr, eRow, Dis, edges);
  init_k<<<N_ALL / 256, 256, 0, stream>>>(lab, labflag, xv, rv, dv0);

  const double theta = 1.0, delta = 0.992;
  const double sigma1 = theta / delta;
  double rho = delta / theta;
  float2* dA = dv0;
  float2* dB = dv1;
  for (int k = 0; k < NIT_CH; ++k) {
    const int last = (k == NIT_CH - 1);
    const double rho_new = 1.0 / (2.0 * sigma1 - rho);
    const float c1 = (float)(rho_new * rho);
    const float c2 = (float)(2.0 * rho_new / delta);
    chebit_k<<<N_ALL / 8, 512, 0, stream>>>(edges, rowPtr, dA, dB, xv, rv,
                                            c1, c2, last);
    rho = rho_new;
    float2* t = dA; dA = dB; dB = t;
  }
  out_k<<<(N_ALL - N_LAB) / 256, 256, 0, stream>>>(xv, out);
}